// Round 11
// baseline (60.698 us; speedup 1.0000x reference)
//
#include <hip/hip_runtime.h>
#include <hip/hip_bf16.h>

#define BB  4
#define SS  127
#define DD  768
#define HH  12
#define HDl 64
#define NSl 128

typedef __attribute__((ext_vector_type(8))) short short8;
typedef __attribute__((ext_vector_type(4))) float f32x4;

// ---- workspace layout (floats) ----
constexpr int OFF_P   = 0;                          // B*S*D
constexpr int OFF_Q   = OFF_P  + BB*SS*DD;          // B*S*D (Q' = desc@eW1[D:] + eb1)
constexpr int OFF_V   = OFF_Q  + BB*SS*DD;          // B*NS*D
constexpr int OFF_QA  = OFF_V  + BB*NSl*DD;         // B*NS*H
constexpr int OFF_KA  = OFF_QA + BB*NSl*HH;         // B*NS*H
constexpr int OFF_W2B = OFF_KA + BB*NSl*HH;         // 16*768 bf16 = 6144 floats
constexpr int OFF_WQA = OFF_W2B + 6144;             // H*D
constexpr int OFF_WKA = OFF_WQA + HH*DD;            // H*D
constexpr int OFF_BF  = OFF_WKA + HH*DD;            // 36
constexpr int OFF_SP  = OFF_BF + 64;                // B*128 each
constexpr int OFF_SSP = OFF_SP + BB*128;
constexpr int OFF_SQ  = OFF_SSP + BB*128;
constexpr int OFF_SSQ = OFF_SQ + BB*128;
constexpr int OFF_EL  = OFF_SSQ + BB*128;           // B*H*NS*NS

__device__ inline unsigned short f2bf(float f) {
    unsigned int u = __builtin_bit_cast(unsigned int, f);
    u += 0x7fffu + ((u >> 16) & 1u);
    return (unsigned short)(u >> 16);
}

// v_cvt_pk_bf16_f32: D[15:0]=bf16(lo), D[31:16]=bf16(hi), RNE (== f2bf)
__device__ inline unsigned int cvtpk(float lo, float hi) {
    unsigned int r;
    asm volatile("v_cvt_pk_bf16_f32 %0, %1, %2" : "=v"(r) : "v"(lo), "v"(hi));
    return r;
}

__device__ inline short8 pack8(float4 a, float4 b) {
    int4 ti = { (int)cvtpk(a.x, a.y), (int)cvtpk(a.z, a.w),
                (int)cvtpk(b.x, b.y), (int)cvtpk(b.z, b.w) };
    return __builtin_bit_cast(short8, ti);
}

// unpack short8 (bf16) -> 8 floats
__device__ inline void unpack8(short8 s, float* f) {
    int4 u = __builtin_bit_cast(int4, s);
    f[0] = __builtin_bit_cast(float, u.x << 16);
    f[1] = __builtin_bit_cast(float, u.x & 0xffff0000);
    f[2] = __builtin_bit_cast(float, u.y << 16);
    f[3] = __builtin_bit_cast(float, u.y & 0xffff0000);
    f[4] = __builtin_bit_cast(float, u.z << 16);
    f[5] = __builtin_bit_cast(float, u.z & 0xffff0000);
    f[6] = __builtin_bit_cast(float, u.w << 16);
    f[7] = __builtin_bit_cast(float, u.w & 0xffff0000);
}

// ---------------------------------------------------------------------------
// MEGA1: one launch, role-dispatched.
//   blocks [0,96):    PQ GEMM tiles; blocks [96,192): V GEMM; rest: fold.
// ---------------------------------------------------------------------------
constexpr int NB_PQ   = 96;
constexpr int NB_V    = 96;
constexpr int FOLD_T  = 3 * HH * DD + 36 + 4 * DD;   // 30756
constexpr int NB_FOLD = (FOLD_T + 511) / 512;        // 61

__global__ __launch_bounds__(512) void mega1(
        const float* __restrict__ desc, const float* __restrict__ nve,
        const float* __restrict__ eW1, const float* __restrict__ Wv,
        const float* __restrict__ bv, const float* __restrict__ eb1,
        const float* __restrict__ Wq, const float* __restrict__ Wk,
        const float* __restrict__ eW2,
        const float* __restrict__ bq, const float* __restrict__ bk,
        const float* __restrict__ eb2, const float* __restrict__ aW,
        float* __restrict__ P, float* __restrict__ Qm, float* __restrict__ V,
        unsigned short* __restrict__ W2Bu, float* __restrict__ WQA,
        float* __restrict__ WKA, float* __restrict__ bfold) {
    const int bid = blockIdx.x;
    const int tid = threadIdx.x;

    if (bid >= NB_PQ + NB_V) {
        // ---------------- fold role ----------------
        int idx = (bid - NB_PQ - NB_V) * 512 + tid;
        const int total = 3 * HH * DD;
        if (idx < total) {
            int which = idx / (HH * DD);
            int r = idx % (HH * DD);
            int h = r / DD;
            int c = r % DD;
            const float* W = (which == 0) ? eW2 : (which == 1) ? Wq : Wk;
            const float* a = (which == 0) ? (aW + 2 * HDl) : (which == 1) ? aW : (aW + HDl);
            float s = 0.f;
            #pragma unroll 8
            for (int d = 0; d < HDl; ++d) s += W[c * DD + h * HDl + d] * a[d];
            if (which == 0) W2Bu[h * DD + c] = f2bf(s);
            else if (which == 1) WQA[h * DD + c] = s;
            else WKA[h * DD + c] = s;
        } else if (idx < total + 36) {
            int r = idx - total;
            int which = r / HH, h = r % HH;
            const float* bb = (which == 0) ? eb2 : (which == 1) ? bq : bk;
            const float* a = (which == 0) ? (aW + 2 * HDl) : (which == 1) ? aW : (aW + HDl);
            float s = 0.f;
            for (int d = 0; d < HDl; ++d) s += bb[h * HDl + d] * a[d];
            bfold[r] = s;
        } else if (idx < FOLD_T) {
            W2Bu[12 * DD + (idx - total - 36)] = 0;   // pad heads 12..15
        }
        return;
    }

    // ---------------- GEMM roles ----------------
    const bool pq = (bid < NB_PQ);
    const int r = pq ? bid : bid - NB_PQ;
    const int bcol = (r % 12) * 64;
    const int brow = (r / 12) * 64;
    const float* A  = pq ? desc : nve;
    const float* B0 = pq ? eW1 : Wv;
    const int M = pq ? (BB * SS) : (BB * NSl);

    __shared__ short lds[3 * 64 * 64];   // As | Bs0 | Bs1
    short* As  = lds;
    short* Bs0 = lds + 4096;
    short* Bs1 = lds + 8192;

    const int arow = tid >> 3, akc = (tid & 7) * 8;
    const int abyte = (arow * 128 + akc * 2) ^ ((arow & 7) << 4);
    const int bn = tid & 63, bg = tid >> 6;
    const int bbyte = (bn * 128 + bg * 16) ^ ((bn & 7) << 4);

    const int gm = brow + arow;
    const float* arow_p = A + gm * DD + akc;

    short8 gA, gB0, gB1;
    auto loadA = [&](int k0) {
        float4 f0 = {0,0,0,0}, f1 = {0,0,0,0};
        if (gm < M) {
            f0 = *(const float4*)(arow_p + k0);
            f1 = *(const float4*)(arow_p + k0 + 4);
        }
        gA = pack8(f0, f1);
    };
    auto loadB = [&](const float* Bm, int k0, short8& dst) {
        float v[8];
        #pragma unroll
        for (int q = 0; q < 8; ++q)
            v[q] = Bm[(k0 + bg * 8 + q) * DD + bcol + bn];
        int4 ti = { (int)cvtpk(v[0], v[1]), (int)cvtpk(v[2], v[3]),
                    (int)cvtpk(v[4], v[5]), (int)cvtpk(v[6], v[7]) };
        dst = __builtin_bit_cast(short8, ti);
    };

    loadA(0);
    loadB(B0, 0, gB0);
    if (pq) loadB(eW1 + DD * DD, 0, gB1);

    const int lane = tid & 63;
    const int w = tid >> 6;
    const int wr = w >> 1, wc = w & 1;
    const int l15 = lane & 15;

    f32x4 acc0[2] = {};
    f32x4 acc1[2] = {};

    for (int k0 = 0; k0 < DD; k0 += 64) {
        *(short8*)((char*)As + abyte) = gA;
        *(short8*)((char*)Bs0 + bbyte) = gB0;
        if (pq) *(short8*)((char*)Bs1 + bbyte) = gB1;
        __syncthreads();
        if (k0 + 64 < DD) {
            loadA(k0 + 64);
            loadB(B0, k0 + 64, gB0);
            if (pq) loadB(eW1 + DD * DD, k0 + 64, gB1);
        }
        #pragma unroll
        for (int ks = 0; ks < 2; ++ks) {
            const int kb = ks * 64 + ((lane >> 4) << 4);
            int row = wr * 16 + l15;
            short8 af = *(const short8*)((char*)As + ((row * 128 + kb) ^ ((row & 7) << 4)));
            #pragma unroll
            for (int ni = 0; ni < 2; ++ni) {
                int col = wc * 32 + ni * 16 + l15;
                int cb = (col * 128 + kb) ^ ((col & 7) << 4);
                short8 b0 = *(const short8*)((char*)Bs0 + cb);
                acc0[ni] = __builtin_amdgcn_mfma_f32_16x16x32_bf16(af, b0, acc0[ni], 0, 0, 0);
                if (pq) {
                    short8 b1 = *(const short8*)((char*)Bs1 + cb);
                    acc1[ni] = __builtin_amdgcn_mfma_f32_16x16x32_bf16(af, b1, acc1[ni], 0, 0, 0);
                }
            }
        }
        __syncthreads();
    }

    #pragma unroll
    for (int ni = 0; ni < 2; ++ni) {
        int gcol = bcol + wc * 32 + ni * 16 + l15;
        float bias0 = pq ? 0.f : bv[gcol];
        float bias1 = pq ? eb1[gcol] : 0.f;
        #pragma unroll
        for (int rr = 0; rr < 4; ++rr) {
            int grow = brow + wr * 16 + ((lane >> 4) << 2) + rr;
            if (grow < M) {
                if (pq) {
                    P[grow * DD + gcol]  = acc0[ni][rr];
                    Qm[grow * DD + gcol] = acc1[ni][rr] + bias1;
                } else {
                    V[grow * DD + gcol] = acc0[ni][rr] + bias0;
                }
            }
        }
    }
}

// ---------------------------------------------------------------------------
// Merged rowstat + qk: one wave per task.
// ---------------------------------------------------------------------------
__global__ void statqk_kernel(const float* __restrict__ Pp, const float* __restrict__ Qp,
                              const float* __restrict__ nve,
                              const float* __restrict__ WQA, const float* __restrict__ WKA,
                              const float* __restrict__ bfold,
                              float* __restrict__ SP, float* __restrict__ SSP,
                              float* __restrict__ SQ, float* __restrict__ SSQ,
                              float* __restrict__ qa, float* __restrict__ ka) {
    int wid = blockIdx.x * 4 + (threadIdx.x >> 6);
    int lane = threadIdx.x & 63;
    const int NSTAT = BB * SS * 2;
    if (wid < NSTAT) {
        int which = wid & 1;
        int row = (wid >> 1) % SS;
        int b = (wid >> 1) / SS;
        const float* src = (which ? Qp : Pp) + (b * SS + row) * DD;
        float s = 0.f, ss = 0.f;
        #pragma unroll
        for (int r = 0; r < 12; ++r) {
            float v = src[lane + 64 * r];
            s += v;
            ss += v * v;
        }
        #pragma unroll
        for (int off = 32; off; off >>= 1) {
            s += __shfl_xor(s, off);
            ss += __shfl_xor(ss, off);
        }
        if (lane == 0) {
            (which ? SQ : SP)[b * 128 + row] = s;
            (which ? SSQ : SSP)[b * 128 + row] = ss;
        }
    } else {
        int t2 = wid - NSTAT;
        if (t2 >= BB * NSl * HH * 2) return;
        int which = t2 & 1;
        int r = t2 >> 1;
        int h = r % HH;
        int t = (r / HH) % NSl;
        int b = r / (HH * NSl);
        const float* W = (which ? WKA : WQA) + h * DD;
        const float* row = nve + (b * NSl + t) * DD;
        float s = 0.f;
        #pragma unroll
        for (int rr = 0; rr < 12; ++rr) {
            int c = lane + 64 * rr;
            s += row[c] * W[c];
        }
        #pragma unroll
        for (int off = 32; off; off >>= 1) s += __shfl_xor(s, off);
        if (lane == 0)
            (which ? ka : qa)[(b * NSl + t) * HH + h] = s + bfold[12 + which * 12 + h];
    }
}

// ---------------------------------------------------------------------------
// Pair MFMA: block = (b, 16x16 pi/qj tile), 512 threads (8 waves).
// External row stats (statqk), in-block Gram, cvt_pk repack.
// ---------------------------------------------------------------------------
__global__ __launch_bounds__(512) void pair_mfma(
        const float* __restrict__ Pp, const float* __restrict__ Qp,
        const float* __restrict__ ln_g, const float* __restrict__ ln_b,
        const unsigned short* __restrict__ W2Bu,
        const float* __restrict__ SP, const float* __restrict__ SSP,
        const float* __restrict__ SQ, const float* __restrict__ SSQ,
        const float* __restrict__ bfold,
        float* __restrict__ e_log) {
    __shared__ short pB[16 * 768];    // 24KB
    __shared__ short qB[16 * 768];    // 24KB
    __shared__ float gbl[2 * 768];    // 6KB

    const int b   = blockIdx.z;
    const int pi0 = blockIdx.y * 16, qj0 = blockIdx.x * 16;
    const int tid = threadIdx.x;

    {
        int row = tid >> 5;
        int ccb = tid & 31;
        const float* psrc = Pp + (b * SS + min(pi0 + row, SS - 1)) * DD;
        const float* qsrc = Qp + (b * SS + min(qj0 + row, SS - 1)) * DD;
        #pragma unroll
        for (int it = 0; it < 3; ++it) {
            int cc = ccb + it * 32;
            int byte = (row * 1536 + cc * 16) ^ ((row & 7) << 4);
            float4 a0 = *(const float4*)(psrc + cc * 8);
            float4 a1 = *(const float4*)(psrc + cc * 8 + 4);
            *(short8*)((char*)pB + byte) = pack8(a0, a1);
            a0 = *(const float4*)(qsrc + cc * 8);
            a1 = *(const float4*)(qsrc + cc * 8 + 4);
            *(short8*)((char*)qB + byte) = pack8(a0, a1);
        }
    }
    if (tid < 384) {
        int c = tid * 4;
        float4 v = (tid < 192) ? *(const float4*)(ln_g + c)
                               : *(const float4*)(ln_b + (c - 768));
        *(float4*)(gbl + c) = v;
    }
    __syncthreads();

    const int lane = tid & 63;
    const int w    = tid >> 6;
    const int l15  = lane & 15;
    const int kg   = lane >> 4;

    f32x4 gacc = {};
    #pragma unroll 4
    for (int ks = 0; ks < 24; ++ks) {
        int cb = ks * 64 + kg * 16;
        short8 ap = *(const short8*)((char*)pB + ((l15 * 1536 + cb) ^ ((l15 & 7) << 4)));
        short8 aq = *(const short8*)((char*)qB + ((l15 * 1536 + cb) ^ ((l15 & 7) << 4)));
        gacc = __builtin_amdgcn_mfma_f32_16x16x32_bf16(ap, aq, gacc, 0, 0, 0);
    }

    float al[2], be[2];
    #pragma unroll
    for (int s = 0; s < 2; ++s) {
        int pl = 2 * w + s;
        int src = ((pl >> 2) << 4) | l15;
        int rsel = pl & 3;
        float gg = (rsel == 0) ? gacc[0] : (rsel == 1) ? gacc[1]
                 : (rsel == 2) ? gacc[2] : gacc[3];
        gg = __shfl(gg, src);
        int pig = min(pi0 + pl, SS - 1);
        int qjg = min(qj0 + l15, SS - 1);
        float mean = (SP[b * 128 + pig] + SQ[b * 128 + qjg]) * (1.f / DD);
        float sumsq = SSP[b * 128 + pig] + 2.f * gg + SSQ[b * 128 + qjg];
        float var = sumsq * (1.f / DD) - mean * mean;
        float a = rsqrtf(var + 1e-5f);
        al[s] = a;
        be[s] = -mean * a;
    }

    const unsigned short* wrow = W2Bu + l15 * 768;
    const int r0 = 2 * w, r1 = 2 * w + 1;
    const int p0base = r0 * 1536, p1base = r1 * 1536;
    const int p0x = (r0 & 7) << 4, p1x = (r1 & 7) << 4;
    f32x4 acc0 = {}, acc1 = {};

    #pragma unroll 2
    for (int ks = 0; ks < 24; ++ks) {
        const int c0 = ks * 32 + kg * 8;
        short8 bfg = *(const short8*)(wrow + c0);
        f32x4 g0 = *(const f32x4*)(gbl + c0);
        f32x4 g1 = *(const f32x4*)(gbl + c0 + 4);
        f32x4 bb0 = *(const f32x4*)(gbl + 768 + c0);
        f32x4 bb1 = *(const f32x4*)(gbl + 768 + c0 + 4);
        float gv[8] = {g0.x, g0.y, g0.z, g0.w, g1.x, g1.y, g1.z, g1.w};
        float bv8[8] = {bb0.x, bb0.y, bb0.z, bb0.w, bb1.x, bb1.y, bb1.z, bb1.w};

        short8 q8 = *(const short8*)((char*)qB + ((l15 * 1536 + c0 * 2) ^ ((l15 & 7) << 4)));
        float qf[8];
        unpack8(q8, qf);

        short8 p8 = *(const short8*)((char*)pB + ((p0base + c0 * 2) ^ p0x));
        float pf[8];
        unpack8(p8, pf);
        float y[8];
        #pragma unroll
        for (int j = 0; j < 8; ++j) {
            float t = pf[j] + qf[j];
            float u = __builtin_fmaf(al[0], t, be[0]);
            y[j] = fmaxf(__builtin_fmaf(gv[j], u, bv8[j]), 0.f);
        }
        {
            int4 ti = { (int)cvtpk(y[0], y[1]), (int)cvtpk(y[2], y[3]),
                        (int)cvtpk(y[4], y[5]), (int)cvtpk(y[6], y[7]) };
            short8 ya = __builtin_bit_cast(short8, ti);
            acc0 = __builtin_amdgcn_mfma_f32_16x16x32_bf16(ya, bfg, acc0, 0, 0, 0);
        }

        p8 = *(const short8*)((char*)pB + ((p1base + c0 * 2) ^ p1x));
        unpack8(p8, pf);
        #pragma unroll
        for (int j = 0; j < 8; ++j) {
            float t = pf[j] + qf[j];
            float u = __builtin_fmaf(al[1], t, be[1]);
            y[j] = fmaxf(__builtin_fmaf(gv[j], u, bv8[j]), 0.f);
        }
        {
            int4 ti = { (int)cvtpk(y[0], y[1]), (int)cvtpk(y[2], y[3]),
                        (int)cvtpk(y[4], y[5]), (int)cvtpk(y[6], y[7]) };
            short8 ya = __builtin_bit_cast(short8, ti);
            acc1 = __builtin_amdgcn_mfma_f32_16x16x32_bf16(ya, bfg, acc1, 0, 0, 0);
        }
    }

    if (l15 < HH) {
        const float badd = bfold[l15];
        #pragma unroll
        for (int s = 0; s < 2; ++s) {
            int pig = pi0 + 2 * w + s;
            if (pig >= SS) continue;
            f32x4 A = s ? acc1 : acc0;
            #pragma unroll
            for (int r = 0; r < 4; ++r) {
                int qjg = qj0 + (kg << 2) + r;
                if (qjg < SS) {
                    int i = (pig == qjg) ? 0 : (pig + 1);
                    e_log[(((b * HH + l15) * NSl) + i) * NSl + (qjg + 1)] = A[r] + badd;
                }
            }
        }
    }
}

// ---------------------------------------------------------------------------
// Softmax + context v6: block = (iq, h, b), 512 threads (8 waves).
// Context via PV MFMA (Vt bf16 swizzled + plb bf16 swizzled).
// ---------------------------------------------------------------------------
__global__ __launch_bounds__(512) void softmax_ctx_kernel(
        const float* __restrict__ e_log,
        const float* __restrict__ qa, const float* __restrict__ ka,
        const float* __restrict__ mask_M, const float* __restrict__ ab,
        const float* __restrict__ V,
        float* __restrict__ out) {
    __shared__ short Vt[64 * 128];    // [d][j] bf16 swizzled, 16KB
    __shared__ short plb[32 * 128];   // [i_loc][j] bf16 swizzled, 8KB
    __shared__ float kal[NSl];

    const int b = blockIdx.z;
    const int h = blockIdx.y;
    const int iq = blockIdx.x;
    const int tid = threadIdx.x;
    const int lane = tid & 63;
    const int w = tid >> 6;

    // ---- stage Vt (transposed bf16, swizzled) ----
    {
        int j = tid >> 2;
        int dq = (tid & 3) * 16;
        const float* src = V + (b * NSl + j) * DD + h * HDl + dq;
        float4 f0 = *(const float4*)(src);
        float4 f1 = *(const float4*)(src + 4);
        float4 f2 = *(const float4*)(src + 8);
        float4 f3 = *(const float4*)(src + 12);
        float vv[16] = {f0.x,f0.y,f0.z,f0.w, f1.x,f1.y,f1.z,f1.w,
                        f2.x,f2.y,f2.z,f2.w, f3.x,f3.y,f3.z,f3.w};
        #pragma unroll
        for (int t = 0; t < 16; ++t) {
            int d = dq + t;
            int byte = (d * 256 + j * 2) ^ ((d & 7) << 4);
            *(short*)((char*)Vt + byte) = (short)f2bf(vv[t]);
        }
    }
    if (tid < NSl) kal[tid] = ka[(b * NSl + tid) * HH + h];
    __syncthreads();

    const float abv = ab[0];

    // ---- softmax phase (no block barriers) ----
    for (int rr = 0; rr < 4; ++rr) {
        const int il = w * 4 + rr;           // local row 0..31
        const int i = iq * 32 + il;
        const float qv = qa[(b * NSl + i) * HH + h];
        const float* e_row = e_log + (((b * HH + h) * NSl) + i) * NSl;

        float lg[2];
        bool valid[2];
        #pragma unroll
        for (int s = 0; s < 2; ++s) {
            int j = 1 + lane + 64 * s;
            bool v = (j < NSl) && !(i >= 1 && j == i);
            float l = -1e30f;
            if (v) {
                l = e_row[j] + qv + kal[j] + abv;
                if (i >= 1) {
                    float p = mask_M[((b * HH + h) * SS + (i - 1)) * SS + (j - 1)];
                    p = fminf(fmaxf(p, 1e-6f), 1.0f - 1e-6f);
                    l += __logf(p / (1.0f - p));
                }
            }
            lg[s] = l;
            valid[s] = v;
        }
        float m = fmaxf(lg[0], lg[1]);
        #pragma unroll
        for (int off = 32; off; off >>= 1) m = fmaxf(m, __shfl_xor(m, off));
        float e0 = valid[0] ? __expf(lg[0] - m) : 0.f;
        float e1 = valid[1] ? __expf(lg[1] - m) : 0.f;
        float s = e0 + e1;
        #pragma unroll
        for (int off = 32; off; off >>= 1) s += __shfl_xor(s, off);
        const float inv = 1.0f / s;

        const float p0 = e0 * inv, p1 = e1 * inv;

        float* attn_row = out + BB * NSl * HH * HDl + (((b * HH + h) * NSl) + i) * NSl;
        attn_row[1 + lane] = p0;
        if (65 + lane < NSl) attn_row[65 + lane] = p1;
        if (lane == 0) attn_row[0] = 0.f;

        // probs -> plb bf16 (swizzled). Per-wave-private rows; no barrier.
        {
            int byte0 = (il * 256 + (1 + lane) * 2) ^ ((il & 7) << 4);
            *(short*)((char*)plb + byte0) = (short)f2bf(p0);
            if (65 + lane < NSl) {
                int byte1 = (il * 256 + (65 + lane) * 2) ^ ((il & 7) << 4);
                *(short*)((char*)plb + byte1) = (short)f2bf(p1);
            }
            if (lane == 0) {
                int byteZ = (il * 256) ^ ((il & 7) << 4);
                *(short*)((char*)plb + byteZ) = 0;
            }
        }
    }
    __syncthreads();

    // ---- context via MFMA: wave w -> itile = w>>2 (16 i), dtile = w&3 (16 d)
    const int l15 = lane & 15;
    const int kg  = lane >> 4;
    const int itile = w >> 2, dtile = w & 3;
    const int arow  = itile * 16 + l15;
    const int bcold = dtile * 16 + l15;
    f32x4 acc = {};
    #pragma unroll
    for (int ks = 0; ks < 4; ++ks) {
        int kb = (ks * 32 + kg * 8) * 2;
        short8 af = *(const short8*)((char*)plb + ((arow * 256 + kb) ^ ((arow & 7) << 4)));
        short8 bf = *(const short8*)((char*)Vt  + ((bcold * 256 + kb) ^ ((bcold & 7) << 4)));
        acc = __builtin_amdgcn_mfma_f32_16x16x32_bf16(af, bf, acc, 0, 0, 0);
    }
    #pragma unroll
    for (int r = 0; r < 4; ++r) {
        int i = iq * 32 + itile * 16 + kg * 4 + r;
        out[((b * NSl + i) * HH + h) * HDl + dtile * 16 + l15] = acc[r];
    }
}

// ---------------------------------------------------------------------------
extern "C" void kernel_launch(void* const* d_in, const int* in_sizes, int n_in,
                              void* d_out, int out_size, void* d_ws, size_t ws_size,
                              hipStream_t stream) {
    const float* desc   = (const float*)d_in[0];
    const float* nve    = (const float*)d_in[1];
    const float* mask_M = (const float*)d_in[2];
    const float* Wq     = (const float*)d_in[3];
    const float* bq     = (const float*)d_in[4];
    const float* Wk     = (const float*)d_in[5];
    const float* bk     = (const float*)d_in[6];
    const float* Wv     = (const float*)d_in[7];
    const float* bv     = (const float*)d_in[8];
    const float* eW1    = (const float*)d_in[9];
    const float* eb1    = (const float*)d_in[10];
    const float* ln_g   = (const float*)d_in[11];
    const float* ln_b   = (const float*)d_in[12];
    const float* eW2    = (const float*)d_in[13];
    const float* eb2    = (const float*)d_in[14];
    const float* aW     = (const float*)d_in[15];
    const float* ab     = (const float*)d_in[16];

    float* ws  = (float*)d_ws;
    float* out = (float*)d_out;
    unsigned short* W2Bu = (unsigned short*)(ws + OFF_W2B);

    mega1<<<NB_PQ + NB_V + NB_FOLD, 512, 0, stream>>>(
        desc, nve, eW1, Wv, bv, eb1,
        Wq, Wk, eW2, bq, bk, eb2, aW,
        ws + OFF_P, ws + OFF_Q, ws + OFF_V,
        W2Bu, ws + OFF_WQA, ws + OFF_WKA, ws + OFF_BF);

    statqk_kernel<<<(BB * SS * 2 + BB * NSl * HH * 2 + 3) / 4, 256, 0, stream>>>(
        ws + OFF_P, ws + OFF_Q, nve, ws + OFF_WQA, ws + OFF_WKA, ws + OFF_BF,
        ws + OFF_SP, ws + OFF_SSP, ws + OFF_SQ, ws + OFF_SSQ,
        ws + OFF_QA, ws + OFF_KA);

    pair_mfma<<<dim3(8, 8, BB), 512, 0, stream>>>(
        ws + OFF_P, ws + OFF_Q, ln_g, ln_b, W2Bu,
        ws + OFF_SP, ws + OFF_SSP, ws + OFF_SQ, ws + OFF_SSQ,
        ws + OFF_BF, ws + OFF_EL);

    softmax_ctx_kernel<<<dim3(4, HH, BB), 512, 0, stream>>>(
        ws + OFF_EL, ws + OFF_QA, ws + OFF_KA, mask_M, ab, ws + OFF_V, out);
}

// Round 12
// 54.554 us; speedup vs baseline: 1.1126x; 1.1126x over previous
//
#include <hip/hip_runtime.h>
#include <hip/hip_bf16.h>

#define BB  4
#define SS  127
#define DD  768
#define HH  12
#define HDl 64
#define NSl 128

typedef __attribute__((ext_vector_type(8))) short short8;
typedef __attribute__((ext_vector_type(4))) float f32x4;

// ---- workspace layout (floats) ----
constexpr int OFF_P   = 0;                          // B*S*D
constexpr int OFF_Q   = OFF_P  + BB*SS*DD;          // B*S*D (Q' = desc@eW1[D:] + eb1)
constexpr int OFF_V   = OFF_Q  + BB*SS*DD;          // B*NS*D
constexpr int OFF_QA  = OFF_V  + BB*NSl*DD;         // B*NS*H
constexpr int OFF_KA  = OFF_QA + BB*NSl*HH;         // B*NS*H
constexpr int OFF_W2B = OFF_KA + BB*NSl*HH;         // 16*768 bf16 = 6144 floats
constexpr int OFF_WQA = OFF_W2B + 6144;             // H*D
constexpr int OFF_WKA = OFF_WQA + HH*DD;            // H*D
constexpr int OFF_BF  = OFF_WKA + HH*DD;            // 36
constexpr int OFF_EL  = OFF_BF + 64;                // B*H*NS*NS

__device__ inline unsigned short f2bf(float f) {
    unsigned int u = __builtin_bit_cast(unsigned int, f);
    u += 0x7fffu + ((u >> 16) & 1u);
    return (unsigned short)(u >> 16);
}

__device__ inline short8 pack8(float4 a, float4 b) {
    short8 p;
    p[0] = (short)f2bf(a.x); p[1] = (short)f2bf(a.y);
    p[2] = (short)f2bf(a.z); p[3] = (short)f2bf(a.w);
    p[4] = (short)f2bf(b.x); p[5] = (short)f2bf(b.y);
    p[6] = (short)f2bf(b.z); p[7] = (short)f2bf(b.w);
    return p;
}

// unpack short8 (bf16) -> 8 floats
__device__ inline void unpack8(short8 s, float* f) {
    int4 u = __builtin_bit_cast(int4, s);
    f[0] = __builtin_bit_cast(float, u.x << 16);
    f[1] = __builtin_bit_cast(float, u.x & 0xffff0000);
    f[2] = __builtin_bit_cast(float, u.y << 16);
    f[3] = __builtin_bit_cast(float, u.y & 0xffff0000);
    f[4] = __builtin_bit_cast(float, u.z << 16);
    f[5] = __builtin_bit_cast(float, u.z & 0xffff0000);
    f[6] = __builtin_bit_cast(float, u.w << 16);
    f[7] = __builtin_bit_cast(float, u.w & 0xffff0000);
}

// v_cvt_pk_bf16_f32: D[15:0]=bf16(lo), D[31:16]=bf16(hi), RNE
__device__ inline unsigned int cvtpk(float lo, float hi) {
    unsigned int r;
    asm volatile("v_cvt_pk_bf16_f32 %0, %1, %2" : "=v"(r) : "v"(lo), "v"(hi));
    return r;
}

// ---------------------------------------------------------------------------
// MEGA1: one launch, role-dispatched (round-10 version).
// ---------------------------------------------------------------------------
constexpr int NB_PQ   = 96;
constexpr int NB_V    = 96;
constexpr int FOLD_T  = 3 * HH * DD + 36 + 4 * DD;   // 30756
constexpr int NB_FOLD = (FOLD_T + 511) / 512;        // 61

__global__ __launch_bounds__(512) void mega1(
        const float* __restrict__ desc, const float* __restrict__ nve,
        const float* __restrict__ eW1, const float* __restrict__ Wv,
        const float* __restrict__ bv, const float* __restrict__ eb1,
        const float* __restrict__ Wq, const float* __restrict__ Wk,
        const float* __restrict__ eW2,
        const float* __restrict__ bq, const float* __restrict__ bk,
        const float* __restrict__ eb2, const float* __restrict__ aW,
        float* __restrict__ P, float* __restrict__ Qm, float* __restrict__ V,
        unsigned short* __restrict__ W2Bu, float* __restrict__ WQA,
        float* __restrict__ WKA, float* __restrict__ bfold) {
    const int bid = blockIdx.x;
    const int tid = threadIdx.x;

    if (bid >= NB_PQ + NB_V) {
        // ---------------- fold role ----------------
        int idx = (bid - NB_PQ - NB_V) * 512 + tid;
        const int total = 3 * HH * DD;
        if (idx < total) {
            int which = idx / (HH * DD);
            int r = idx % (HH * DD);
            int h = r / DD;
            int c = r % DD;
            const float* W = (which == 0) ? eW2 : (which == 1) ? Wq : Wk;
            const float* a = (which == 0) ? (aW + 2 * HDl) : (which == 1) ? aW : (aW + HDl);
            float s = 0.f;
            #pragma unroll 8
            for (int d = 0; d < HDl; ++d) s += W[c * DD + h * HDl + d] * a[d];
            if (which == 0) W2Bu[h * DD + c] = f2bf(s);
            else if (which == 1) WQA[h * DD + c] = s;
            else WKA[h * DD + c] = s;
        } else if (idx < total + 36) {
            int r = idx - total;
            int which = r / HH, h = r % HH;
            const float* bb = (which == 0) ? eb2 : (which == 1) ? bq : bk;
            const float* a = (which == 0) ? (aW + 2 * HDl) : (which == 1) ? aW : (aW + HDl);
            float s = 0.f;
            for (int d = 0; d < HDl; ++d) s += bb[h * HDl + d] * a[d];
            bfold[r] = s;
        } else if (idx < FOLD_T) {
            W2Bu[12 * DD + (idx - total - 36)] = 0;   // pad heads 12..15
        }
        return;
    }

    // ---------------- GEMM roles ----------------
    const bool pq = (bid < NB_PQ);
    const int r = pq ? bid : bid - NB_PQ;
    const int bcol = (r % 12) * 64;
    const int brow = (r / 12) * 64;
    const float* A  = pq ? desc : nve;
    const float* B0 = pq ? eW1 : Wv;
    const int M = pq ? (BB * SS) : (BB * NSl);

    __shared__ short lds[3 * 64 * 64];   // As | Bs0 | Bs1
    short* As  = lds;
    short* Bs0 = lds + 4096;
    short* Bs1 = lds + 8192;

    const int arow = tid >> 3, akc = (tid & 7) * 8;
    const int abyte = (arow * 128 + akc * 2) ^ ((arow & 7) << 4);
    const int bn = tid & 63, bg = tid >> 6;
    const int bbyte = (bn * 128 + bg * 16) ^ ((bn & 7) << 4);

    const int gm = brow + arow;
    const float* arow_p = A + gm * DD + akc;

    short8 gA, gB0, gB1;
    auto loadA = [&](int k0) {
        float4 f0 = {0,0,0,0}, f1 = {0,0,0,0};
        if (gm < M) {
            f0 = *(const float4*)(arow_p + k0);
            f1 = *(const float4*)(arow_p + k0 + 4);
        }
        gA = pack8(f0, f1);
    };
    auto loadB = [&](const float* Bm, int k0, short8& dst) {
        float v[8];
        #pragma unroll
        for (int q = 0; q < 8; ++q)
            v[q] = Bm[(k0 + bg * 8 + q) * DD + bcol + bn];
        short8 p;
        #pragma unroll
        for (int q = 0; q < 8; ++q) p[q] = (short)f2bf(v[q]);
        dst = p;
    };

    loadA(0);
    loadB(B0, 0, gB0);
    if (pq) loadB(eW1 + DD * DD, 0, gB1);

    const int lane = tid & 63;
    const int w = tid >> 6;
    const int wr = w >> 1, wc = w & 1;
    const int l15 = lane & 15;

    f32x4 acc0[2] = {};
    f32x4 acc1[2] = {};

    for (int k0 = 0; k0 < DD; k0 += 64) {
        *(short8*)((char*)As + abyte) = gA;
        *(short8*)((char*)Bs0 + bbyte) = gB0;
        if (pq) *(short8*)((char*)Bs1 + bbyte) = gB1;
        __syncthreads();
        if (k0 + 64 < DD) {
            loadA(k0 + 64);
            loadB(B0, k0 + 64, gB0);
            if (pq) loadB(eW1 + DD * DD, k0 + 64, gB1);
        }
        #pragma unroll
        for (int ks = 0; ks < 2; ++ks) {
            const int kb = ks * 64 + ((lane >> 4) << 4);
            int row = wr * 16 + l15;
            short8 af = *(const short8*)((char*)As + ((row * 128 + kb) ^ ((row & 7) << 4)));
            #pragma unroll
            for (int ni = 0; ni < 2; ++ni) {
                int col = wc * 32 + ni * 16 + l15;
                int cb = (col * 128 + kb) ^ ((col & 7) << 4);
                short8 b0 = *(const short8*)((char*)Bs0 + cb);
                acc0[ni] = __builtin_amdgcn_mfma_f32_16x16x32_bf16(af, b0, acc0[ni], 0, 0, 0);
                if (pq) {
                    short8 b1 = *(const short8*)((char*)Bs1 + cb);
                    acc1[ni] = __builtin_amdgcn_mfma_f32_16x16x32_bf16(af, b1, acc1[ni], 0, 0, 0);
                }
            }
        }
        __syncthreads();
    }

    #pragma unroll
    for (int ni = 0; ni < 2; ++ni) {
        int gcol = bcol + wc * 32 + ni * 16 + l15;
        float bias0 = pq ? 0.f : bv[gcol];
        float bias1 = pq ? eb1[gcol] : 0.f;
        #pragma unroll
        for (int rr = 0; rr < 4; ++rr) {
            int grow = brow + wr * 16 + ((lane >> 4) << 2) + rr;
            if (grow < M) {
                if (pq) {
                    P[grow * DD + gcol]  = acc0[ni][rr];
                    Qm[grow * DD + gcol] = acc1[ni][rr] + bias1;
                } else {
                    V[grow * DD + gcol] = acc0[ni][rr] + bias0;
                }
            }
        }
    }
}

// ---------------------------------------------------------------------------
// PAIR+QK merged launch: grid dim3(8, 8, BB+24), 512 threads.
//   z <  BB : pair tile (b=z), in-block row stats + in-block Gram + MFMA
//   z >= BB : qk role — wave computes one qa/ka output (old statqk code)
// ---------------------------------------------------------------------------
__global__ __launch_bounds__(512) void pairqk_kernel(
        const float* __restrict__ Pp, const float* __restrict__ Qp,
        const float* __restrict__ nve,
        const float* __restrict__ ln_g, const float* __restrict__ ln_b,
        const unsigned short* __restrict__ W2Bu,
        const float* __restrict__ WQA, const float* __restrict__ WKA,
        const float* __restrict__ bfold,
        float* __restrict__ qa, float* __restrict__ ka,
        float* __restrict__ e_log) {
    __shared__ short pB[16 * 768];    // 24KB
    __shared__ short qB[16 * 768];    // 24KB
    __shared__ float gbl[2 * 768];    // 6KB
    __shared__ float2 pstat[16];      // (sum, sumsq) per staged P row
    __shared__ float2 qstat[16];

    const int tid = threadIdx.x;

    if (blockIdx.z >= BB) {
        // ---------------- qk role: one wave per output ----------------
        int qb = (blockIdx.z - BB) * 64 + blockIdx.y * 8 + blockIdx.x;   // 0..1535
        int wid = qb * 8 + (tid >> 6);                                   // 0..12287
        int lane = tid & 63;
        int which = wid & 1;
        int r = wid >> 1;
        int h = r % HH;
        int t = (r / HH) % NSl;
        int b = r / (HH * NSl);
        const float* W = (which ? WKA : WQA) + h * DD;
        const float* row = nve + (b * NSl + t) * DD;
        float s = 0.f;
        #pragma unroll
        for (int rr = 0; rr < 12; ++rr) {
            int c = lane + 64 * rr;
            s += row[c] * W[c];
        }
        #pragma unroll
        for (int off = 32; off; off >>= 1) s += __shfl_xor(s, off);
        if (lane == 0)
            (which ? ka : qa)[(b * NSl + t) * HH + h] = s + bfold[12 + which * 12 + h];
        return;
    }

    // ---------------- pair role ----------------
    const int b   = blockIdx.z;
    const int pi0 = blockIdx.y * 16, qj0 = blockIdx.x * 16;

    // ---- stage P,Q rows (bf16, swizzled) + in-block row stats ----
    {
        int row = tid >> 5;
        int ccb = tid & 31;
        const float* psrc = Pp + (b * SS + min(pi0 + row, SS - 1)) * DD;
        const float* qsrc = Qp + (b * SS + min(qj0 + row, SS - 1)) * DD;
        float ps = 0.f, pss = 0.f, qs = 0.f, qss = 0.f;
        #pragma unroll
        for (int it = 0; it < 3; ++it) {
            int cc = ccb + it * 32;
            int byte = (row * 1536 + cc * 16) ^ ((row & 7) << 4);
            float4 a0 = *(const float4*)(psrc + cc * 8);
            float4 a1 = *(const float4*)(psrc + cc * 8 + 4);
            ps  += (a0.x + a0.y + a0.z + a0.w) + (a1.x + a1.y + a1.z + a1.w);
            pss += a0.x*a0.x + a0.y*a0.y + a0.z*a0.z + a0.w*a0.w
                 + a1.x*a1.x + a1.y*a1.y + a1.z*a1.z + a1.w*a1.w;
            *(short8*)((char*)pB + byte) = pack8(a0, a1);
            a0 = *(const float4*)(qsrc + cc * 8);
            a1 = *(const float4*)(qsrc + cc * 8 + 4);
            qs  += (a0.x + a0.y + a0.z + a0.w) + (a1.x + a1.y + a1.z + a1.w);
            qss += a0.x*a0.x + a0.y*a0.y + a0.z*a0.z + a0.w*a0.w
                 + a1.x*a1.x + a1.y*a1.y + a1.z*a1.z + a1.w*a1.w;
            *(short8*)((char*)qB + byte) = pack8(a0, a1);
        }
        #pragma unroll
        for (int off = 16; off; off >>= 1) {
            ps  += __shfl_xor(ps, off);
            pss += __shfl_xor(pss, off);
            qs  += __shfl_xor(qs, off);
            qss += __shfl_xor(qss, off);
        }
        if ((tid & 31) == 0) {
            pstat[tid >> 5] = make_float2(ps, pss);
            qstat[tid >> 5] = make_float2(qs, qss);
        }
    }
    if (tid < 384) {
        int c = tid * 4;
        float4 v = (tid < 192) ? *(const float4*)(ln_g + c)
                               : *(const float4*)(ln_b + (c - 768));
        *(float4*)(gbl + c) = v;
    }
    __syncthreads();

    const int lane = tid & 63;
    const int w    = tid >> 6;
    const int l15  = lane & 15;
    const int kg   = lane >> 4;

    // ---- in-block Gram ----
    f32x4 gacc = {};
    #pragma unroll 4
    for (int ks = 0; ks < 24; ++ks) {
        int cb = ks * 64 + kg * 16;
        short8 ap = *(const short8*)((char*)pB + ((l15 * 1536 + cb) ^ ((l15 & 7) << 4)));
        short8 aq = *(const short8*)((char*)qB + ((l15 * 1536 + cb) ^ ((l15 & 7) << 4)));
        gacc = __builtin_amdgcn_mfma_f32_16x16x32_bf16(ap, aq, gacc, 0, 0, 0);
    }

    // ---- per-pair LN scalars ----
    float al[2], be[2];
    #pragma unroll
    for (int s = 0; s < 2; ++s) {
        int pl = 2 * w + s;
        int src = ((pl >> 2) << 4) | l15;
        int rsel = pl & 3;
        float gg = (rsel == 0) ? gacc[0] : (rsel == 1) ? gacc[1]
                 : (rsel == 2) ? gacc[2] : gacc[3];
        gg = __shfl(gg, src);
        float2 pst = pstat[pl];
        float2 qst = qstat[l15];
        float mean = (pst.x + qst.x) * (1.f / DD);
        float sumsq = pst.y + 2.f * gg + qst.y;
        float var = sumsq * (1.f / DD) - mean * mean;
        float a = rsqrtf(var + 1e-5f);
        al[s] = a;
        be[s] = -mean * a;
    }

    // ---- main loop ----
    const unsigned short* wrow = W2Bu + l15 * 768;
    const int r0 = 2 * w, r1 = 2 * w + 1;
    const int p0base = r0 * 1536, p1base = r1 * 1536;
    const int p0x = (r0 & 7) << 4, p1x = (r1 & 7) << 4;
    f32x4 acc0 = {}, acc1 = {};

    #pragma unroll 2
    for (int ks = 0; ks < 24; ++ks) {
        const int c0 = ks * 32 + kg * 8;
        short8 bfg = *(const short8*)(wrow + c0);
        f32x4 g0 = *(const f32x4*)(gbl + c0);
        f32x4 g1 = *(const f32x4*)(gbl + c0 + 4);
        f32x4 bb0 = *(const f32x4*)(gbl + 768 + c0);
        f32x4 bb1 = *(const f32x4*)(gbl + 768 + c0 + 4);
        float gv[8] = {g0.x, g0.y, g0.z, g0.w, g1.x, g1.y, g1.z, g1.w};
        float bv8[8] = {bb0.x, bb0.y, bb0.z, bb0.w, bb1.x, bb1.y, bb1.z, bb1.w};

        short8 q8 = *(const short8*)((char*)qB + ((l15 * 1536 + c0 * 2) ^ ((l15 & 7) << 4)));
        float qf[8];
        unpack8(q8, qf);

        short8 p8 = *(const short8*)((char*)pB + ((p0base + c0 * 2) ^ p0x));
        float pf[8];
        unpack8(p8, pf);
        float y[8];
        #pragma unroll
        for (int j = 0; j < 8; ++j) {
            float t = pf[j] + qf[j];
            float u = __builtin_fmaf(al[0], t, be[0]);
            y[j] = fmaxf(__builtin_fmaf(gv[j], u, bv8[j]), 0.f);
        }
        {
            int4 ti = { (int)cvtpk(y[0], y[1]), (int)cvtpk(y[2], y[3]),
                        (int)cvtpk(y[4], y[5]), (int)cvtpk(y[6], y[7]) };
            short8 ya = __builtin_bit_cast(short8, ti);
            acc0 = __builtin_amdgcn_mfma_f32_16x16x32_bf16(ya, bfg, acc0, 0, 0, 0);
        }

        p8 = *(const short8*)((char*)pB + ((p1base + c0 * 2) ^ p1x));
        unpack8(p8, pf);
        #pragma unroll
        for (int j = 0; j < 8; ++j) {
            float t = pf[j] + qf[j];
            float u = __builtin_fmaf(al[1], t, be[1]);
            y[j] = fmaxf(__builtin_fmaf(gv[j], u, bv8[j]), 0.f);
        }
        {
            int4 ti = { (int)cvtpk(y[0], y[1]), (int)cvtpk(y[2], y[3]),
                        (int)cvtpk(y[4], y[5]), (int)cvtpk(y[6], y[7]) };
            short8 ya = __builtin_bit_cast(short8, ti);
            acc1 = __builtin_amdgcn_mfma_f32_16x16x32_bf16(ya, bfg, acc1, 0, 0, 0);
        }
    }

    if (l15 < HH) {
        const float badd = bfold[l15];
        #pragma unroll
        for (int s = 0; s < 2; ++s) {
            int pig = pi0 + 2 * w + s;
            if (pig >= SS) continue;
            f32x4 A = s ? acc1 : acc0;
            #pragma unroll
            for (int r = 0; r < 4; ++r) {
                int qjg = qj0 + (kg << 2) + r;
                if (qjg < SS) {
                    int i = (pig == qjg) ? 0 : (pig + 1);
                    e_log[(((b * HH + l15) * NSl) + i) * NSl + (qjg + 1)] = A[r] + badd;
                }
            }
        }
    }
}

// ---------------------------------------------------------------------------
// Softmax + context (round-10 version): PV via MFMA.
// ---------------------------------------------------------------------------
__global__ __launch_bounds__(512) void softmax_ctx_kernel(
        const float* __restrict__ e_log,
        const float* __restrict__ qa, const float* __restrict__ ka,
        const float* __restrict__ mask_M, const float* __restrict__ ab,
        const float* __restrict__ V,
        float* __restrict__ out) {
    __shared__ short Vt[64 * 128];    // [d][j] bf16 swizzled, 16KB
    __shared__ short plb[32 * 128];   // [i_loc][j] bf16 swizzled, 8KB
    __shared__ float kal[NSl];

    const int b = blockIdx.z;
    const int h = blockIdx.y;
    const int iq = blockIdx.x;
    const int tid = threadIdx.x;
    const int lane = tid & 63;
    const int w = tid >> 6;

    // ---- stage Vt (transposed bf16, swizzled) ----
    {
        int j = tid >> 2;
        int dq = (tid & 3) * 16;
        const float* src = V + (b * NSl + j) * DD + h * HDl + dq;
        float4 f0 = *(const float4*)(src);
        float4 f1 = *(const float4*)(src + 4);
        float4 f2 = *(const float4*)(src + 8);
        float4 f3 = *(const float4*)(src + 12);
        float vv[16] = {f0.x,f0.y,f0.z,f0.w, f1.x,f1.y,f1.z,f1.w,
                        f2.x,f2.y,f2.z,f2.w, f3.x,f3.y,f3.z,f3.w};
        #pragma unroll
        for (int t = 0; t < 16; ++t) {
            int d = dq + t;
            int byte = (d * 256 + j * 2) ^ ((d & 7) << 4);
            *(short*)((char*)Vt + byte) = (short)f2bf(vv[t]);
        }
    }
    if (tid < NSl) kal[tid] = ka[(b * NSl + tid) * HH + h];
    __syncthreads();

    const float abv = ab[0];

    // ---- softmax phase (no block barriers) ----
    for (int rr = 0; rr < 4; ++rr) {
        const int il = w * 4 + rr;           // local row 0..31
        const int i = iq * 32 + il;
        const float qv = qa[(b * NSl + i) * HH + h];
        const float* e_row = e_log + (((b * HH + h) * NSl) + i) * NSl;

        float lg[2];
        bool valid[2];
        #pragma unroll
        for (int s = 0; s < 2; ++s) {
            int j = 1 + lane + 64 * s;
            bool v = (j < NSl) && !(i >= 1 && j == i);
            float l = -1e30f;
            if (v) {
                l = e_row[j] + qv + kal[j] + abv;
                if (i >= 1) {
                    float p = mask_M[((b * HH + h) * SS + (i - 1)) * SS + (j - 1)];
                    p = fminf(fmaxf(p, 1e-6f), 1.0f - 1e-6f);
                    l += __logf(p / (1.0f - p));
                }
            }
            lg[s] = l;
            valid[s] = v;
        }
        float m = fmaxf(lg[0], lg[1]);
        #pragma unroll
        for (int off = 32; off; off >>= 1) m = fmaxf(m, __shfl_xor(m, off));
        float e0 = valid[0] ? __expf(lg[0] - m) : 0.f;
        float e1 = valid[1] ? __expf(lg[1] - m) : 0.f;
        float s = e0 + e1;
        #pragma unroll
        for (int off = 32; off; off >>= 1) s += __shfl_xor(s, off);
        const float inv = 1.0f / s;

        const float p0 = e0 * inv, p1 = e1 * inv;

        float* attn_row = out + BB * NSl * HH * HDl + (((b * HH + h) * NSl) + i) * NSl;
        attn_row[1 + lane] = p0;
        if (65 + lane < NSl) attn_row[65 + lane] = p1;
        if (lane == 0) attn_row[0] = 0.f;

        // probs -> plb bf16 (swizzled). Per-wave-private rows; no barrier.
        {
            int byte0 = (il * 256 + (1 + lane) * 2) ^ ((il & 7) << 4);
            *(short*)((char*)plb + byte0) = (short)f2bf(p0);
            if (65 + lane < NSl) {
                int byte1 = (il * 256 + (65 + lane) * 2) ^ ((il & 7) << 4);
                *(short*)((char*)plb + byte1) = (short)f2bf(p1);
            }
            if (lane == 0) {
                int byteZ = (il * 256) ^ ((il & 7) << 4);
                *(short*)((char*)plb + byteZ) = 0;
            }
        }
    }
    __syncthreads();

    // ---- context via MFMA: wave w -> itile = w>>2 (16 i), dtile = w&3 (16 d)
    const int l15 = lane & 15;
    const int kg  = lane >> 4;
    const int itile = w >> 2, dtile = w & 3;
    const int arow  = itile * 16 + l15;
    const int bcold = dtile * 16 + l15;
    f32x4 acc = {};
    #pragma unroll
    for (int ks = 0; ks < 4; ++ks) {
        int kb = (ks * 32 + kg * 8) * 2;
        short8 af = *(const short8*)((char*)plb + ((arow * 256 + kb) ^ ((arow & 7) << 4)));
        short8 bf = *(const short8*)((char*)Vt  + ((bcold * 256 + kb) ^ ((bcold & 7) << 4)));
        acc = __builtin_amdgcn_mfma_f32_16x16x32_bf16(af, bf, acc, 0, 0, 0);
    }
    #pragma unroll
    for (int r = 0; r < 4; ++r) {
        int i = iq * 32 + itile * 16 + kg * 4 + r;
        out[((b * NSl + i) * HH + h) * HDl + dtile * 16 + l15] = acc[r];
    }
}

// ---------------------------------------------------------------------------
extern "C" void kernel_launch(void* const* d_in, const int* in_sizes, int n_in,
                              void* d_out, int out_size, void* d_ws, size_t ws_size,
                              hipStream_t stream) {
    const float* desc   = (const float*)d_in[0];
    const float* nve    = (const float*)d_in[1];
    const float* mask_M = (const float*)d_in[2];
    const float* Wq     = (const float*)d_in[3];
    const float* bq     = (const float*)d_in[4];
    const float* Wk     = (const float*)d_in[5];
    const float* bk     = (const float*)d_in[6];
    const float* Wv     = (const float*)d_in[7];
    const float* bv     = (const float*)d_in[8];
    const float* eW1    = (const float*)d_in[9];
    const float* eb1    = (const float*)d_in[10];
    const float* ln_g   = (const float*)d_in[11];
    const float* ln_b   = (const float*)d_in[12];
    const float* eW2    = (const float*)d_in[13];
    const float* eb2    = (const float*)d_in[14];
    const float* aW     = (const float*)d_in[15];
    const float* ab     = (const float*)d_in[16];

    float* ws  = (float*)d_ws;
    float* out = (float*)d_out;
    unsigned short* W2Bu = (unsigned short*)(ws + OFF_W2B);

    mega1<<<NB_PQ + NB_V + NB_FOLD, 512, 0, stream>>>(
        desc, nve, eW1, Wv, bv, eb1,
        Wq, Wk, eW2, bq, bk, eb2, aW,
        ws + OFF_P, ws + OFF_Q, ws + OFF_V,
        W2Bu, ws + OFF_WQA, ws + OFF_WKA, ws + OFF_BF);

    pairqk_kernel<<<dim3(8, 8, BB + 24), 512, 0, stream>>>(
        ws + OFF_P, ws + OFF_Q, nve, ln_g, ln_b, W2Bu,
        ws + OFF_WQA, ws + OFF_WKA, ws + OFF_BF,
        ws + OFF_QA, ws + OFF_KA, ws + OFF_EL);

    softmax_ctx_kernel<<<dim3(4, HH, BB), 512, 0, stream>>>(
        ws + OFF_EL, ws + OFF_QA, ws + OFF_KA, mask_M, ab, ws + OFF_V, out);
}

// Round 13
// 52.495 us; speedup vs baseline: 1.1563x; 1.0392x over previous
//
#include <hip/hip_runtime.h>
#include <hip/hip_bf16.h>

#define BB  4
#define SS  127
#define DD  768
#define HH  12
#define HDl 64
#define NSl 128

typedef __attribute__((ext_vector_type(8))) short short8;
typedef __attribute__((ext_vector_type(4))) float f32x4;

// ---- workspace layout (floats; P/Q/V now bf16 in same regions) ----
constexpr int OFF_P   = 0;                          // B*S*D bf16
constexpr int OFF_Q   = OFF_P  + BB*SS*DD;          // B*S*D bf16 (Q' = desc@eW1[D:]+eb1)
constexpr int OFF_V   = OFF_Q  + BB*SS*DD;          // B*NS*D bf16
constexpr int OFF_QA  = OFF_V  + BB*NSl*DD;         // B*NS*H f32
constexpr int OFF_KA  = OFF_QA + BB*NSl*HH;         // B*NS*H f32
constexpr int OFF_W2B = OFF_KA + BB*NSl*HH;         // 16*768 bf16 = 6144 floats
constexpr int OFF_WQA = OFF_W2B + 6144;             // H*D f32
constexpr int OFF_WKA = OFF_WQA + HH*DD;            // H*D f32
constexpr int OFF_BF  = OFF_WKA + HH*DD;            // 36
constexpr int OFF_EL  = OFF_BF + 64;                // B*H*NS*NS f32

__device__ inline unsigned short f2bf(float f) {
    unsigned int u = __builtin_bit_cast(unsigned int, f);
    u += 0x7fffu + ((u >> 16) & 1u);
    return (unsigned short)(u >> 16);
}

__device__ inline short8 pack8(float4 a, float4 b) {
    short8 p;
    p[0] = (short)f2bf(a.x); p[1] = (short)f2bf(a.y);
    p[2] = (short)f2bf(a.z); p[3] = (short)f2bf(a.w);
    p[4] = (short)f2bf(b.x); p[5] = (short)f2bf(b.y);
    p[6] = (short)f2bf(b.z); p[7] = (short)f2bf(b.w);
    return p;
}

// unpack short8 (bf16) -> 8 floats
__device__ inline void unpack8(short8 s, float* f) {
    int4 u = __builtin_bit_cast(int4, s);
    f[0] = __builtin_bit_cast(float, u.x << 16);
    f[1] = __builtin_bit_cast(float, u.x & 0xffff0000);
    f[2] = __builtin_bit_cast(float, u.y << 16);
    f[3] = __builtin_bit_cast(float, u.y & 0xffff0000);
    f[4] = __builtin_bit_cast(float, u.z << 16);
    f[5] = __builtin_bit_cast(float, u.z & 0xffff0000);
    f[6] = __builtin_bit_cast(float, u.w << 16);
    f[7] = __builtin_bit_cast(float, u.w & 0xffff0000);
}

// v_cvt_pk_bf16_f32: D[15:0]=bf16(lo), D[31:16]=bf16(hi), RNE
__device__ inline unsigned int cvtpk(float lo, float hi) {
    unsigned int r;
    asm volatile("v_cvt_pk_bf16_f32 %0, %1, %2" : "=v"(r) : "v"(lo), "v"(hi));
    return r;
}

// ---------------------------------------------------------------------------
// MEGA1: one launch, role-dispatched. P/Q/V written as bf16.
// ---------------------------------------------------------------------------
constexpr int NB_PQ   = 96;
constexpr int NB_V    = 96;
constexpr int FOLD_T  = 3 * HH * DD + 36 + 4 * DD;   // 30756
constexpr int NB_FOLD = (FOLD_T + 511) / 512;        // 61

__global__ __launch_bounds__(512) void mega1(
        const float* __restrict__ desc, const float* __restrict__ nve,
        const float* __restrict__ eW1, const float* __restrict__ Wv,
        const float* __restrict__ bv, const float* __restrict__ eb1,
        const float* __restrict__ Wq, const float* __restrict__ Wk,
        const float* __restrict__ eW2,
        const float* __restrict__ bq, const float* __restrict__ bk,
        const float* __restrict__ eb2, const float* __restrict__ aW,
        unsigned short* __restrict__ Pu, unsigned short* __restrict__ Qu,
        unsigned short* __restrict__ Vu,
        unsigned short* __restrict__ W2Bu, float* __restrict__ WQA,
        float* __restrict__ WKA, float* __restrict__ bfold) {
    const int bid = blockIdx.x;
    const int tid = threadIdx.x;

    if (bid >= NB_PQ + NB_V) {
        // ---------------- fold role ----------------
        int idx = (bid - NB_PQ - NB_V) * 512 + tid;
        const int total = 3 * HH * DD;
        if (idx < total) {
            int which = idx / (HH * DD);
            int r = idx % (HH * DD);
            int h = r / DD;
            int c = r % DD;
            const float* W = (which == 0) ? eW2 : (which == 1) ? Wq : Wk;
            const float* a = (which == 0) ? (aW + 2 * HDl) : (which == 1) ? aW : (aW + HDl);
            float s = 0.f;
            #pragma unroll 8
            for (int d = 0; d < HDl; ++d) s += W[c * DD + h * HDl + d] * a[d];
            if (which == 0) W2Bu[h * DD + c] = f2bf(s);
            else if (which == 1) WQA[h * DD + c] = s;
            else WKA[h * DD + c] = s;
        } else if (idx < total + 36) {
            int r = idx - total;
            int which = r / HH, h = r % HH;
            const float* bb = (which == 0) ? eb2 : (which == 1) ? bq : bk;
            const float* a = (which == 0) ? (aW + 2 * HDl) : (which == 1) ? aW : (aW + HDl);
            float s = 0.f;
            for (int d = 0; d < HDl; ++d) s += bb[h * HDl + d] * a[d];
            bfold[r] = s;
        } else if (idx < FOLD_T) {
            W2Bu[12 * DD + (idx - total - 36)] = 0;   // pad heads 12..15
        }
        return;
    }

    // ---------------- GEMM roles ----------------
    const bool pq = (bid < NB_PQ);
    const int r = pq ? bid : bid - NB_PQ;
    const int bcol = (r % 12) * 64;
    const int brow = (r / 12) * 64;
    const float* A  = pq ? desc : nve;
    const float* B0 = pq ? eW1 : Wv;
    const int M = pq ? (BB * SS) : (BB * NSl);

    __shared__ short lds[3 * 64 * 64];   // As | Bs0 | Bs1
    short* As  = lds;
    short* Bs0 = lds + 4096;
    short* Bs1 = lds + 8192;

    const int arow = tid >> 3, akc = (tid & 7) * 8;
    const int abyte = (arow * 128 + akc * 2) ^ ((arow & 7) << 4);
    const int bn = tid & 63, bg = tid >> 6;
    const int bbyte = (bn * 128 + bg * 16) ^ ((bn & 7) << 4);

    const int gm = brow + arow;
    const float* arow_p = A + gm * DD + akc;

    short8 gA, gB0, gB1;
    auto loadA = [&](int k0) {
        float4 f0 = {0,0,0,0}, f1 = {0,0,0,0};
        if (gm < M) {
            f0 = *(const float4*)(arow_p + k0);
            f1 = *(const float4*)(arow_p + k0 + 4);
        }
        gA = pack8(f0, f1);
    };
    auto loadB = [&](const float* Bm, int k0, short8& dst) {
        float v[8];
        #pragma unroll
        for (int q = 0; q < 8; ++q)
            v[q] = Bm[(k0 + bg * 8 + q) * DD + bcol + bn];
        short8 p;
        #pragma unroll
        for (int q = 0; q < 8; ++q) p[q] = (short)f2bf(v[q]);
        dst = p;
    };

    loadA(0);
    loadB(B0, 0, gB0);
    if (pq) loadB(eW1 + DD * DD, 0, gB1);

    const int lane = tid & 63;
    const int w = tid >> 6;
    const int wr = w >> 1, wc = w & 1;
    const int l15 = lane & 15;

    f32x4 acc0[2] = {};
    f32x4 acc1[2] = {};

    for (int k0 = 0; k0 < DD; k0 += 64) {
        *(short8*)((char*)As + abyte) = gA;
        *(short8*)((char*)Bs0 + bbyte) = gB0;
        if (pq) *(short8*)((char*)Bs1 + bbyte) = gB1;
        __syncthreads();
        if (k0 + 64 < DD) {
            loadA(k0 + 64);
            loadB(B0, k0 + 64, gB0);
            if (pq) loadB(eW1 + DD * DD, k0 + 64, gB1);
        }
        #pragma unroll
        for (int ks = 0; ks < 2; ++ks) {
            const int kb = ks * 64 + ((lane >> 4) << 4);
            int row = wr * 16 + l15;
            short8 af = *(const short8*)((char*)As + ((row * 128 + kb) ^ ((row & 7) << 4)));
            #pragma unroll
            for (int ni = 0; ni < 2; ++ni) {
                int col = wc * 32 + ni * 16 + l15;
                int cb = (col * 128 + kb) ^ ((col & 7) << 4);
                short8 b0 = *(const short8*)((char*)Bs0 + cb);
                acc0[ni] = __builtin_amdgcn_mfma_f32_16x16x32_bf16(af, b0, acc0[ni], 0, 0, 0);
                if (pq) {
                    short8 b1 = *(const short8*)((char*)Bs1 + cb);
                    acc1[ni] = __builtin_amdgcn_mfma_f32_16x16x32_bf16(af, b1, acc1[ni], 0, 0, 0);
                }
            }
        }
        __syncthreads();
    }

    #pragma unroll
    for (int ni = 0; ni < 2; ++ni) {
        int gcol = bcol + wc * 32 + ni * 16 + l15;
        float bias0 = pq ? 0.f : bv[gcol];
        float bias1 = pq ? eb1[gcol] : 0.f;
        #pragma unroll
        for (int rr = 0; rr < 4; ++rr) {
            int grow = brow + wr * 16 + ((lane >> 4) << 2) + rr;
            if (grow < M) {
                if (pq) {
                    Pu[grow * DD + gcol] = f2bf(acc0[ni][rr]);
                    Qu[grow * DD + gcol] = f2bf(acc1[ni][rr] + bias1);
                } else {
                    Vu[grow * DD + gcol] = f2bf(acc0[ni][rr] + bias0);
                }
            }
        }
    }
}

// ---------------------------------------------------------------------------
// PAIR+QK merged launch: grid dim3(8, 8, BB+24), 512 threads.
//   z <  BB : pair tile (b=z): stage bf16 P/Q rows + in-block stats + Gram
//   z >= BB : qk role — wave computes one qa/ka output
// ---------------------------------------------------------------------------
__global__ __launch_bounds__(512) void pairqk_kernel(
        const unsigned short* __restrict__ Pu, const unsigned short* __restrict__ Qu,
        const float* __restrict__ nve,
        const float* __restrict__ ln_g, const float* __restrict__ ln_b,
        const unsigned short* __restrict__ W2Bu,
        const float* __restrict__ WQA, const float* __restrict__ WKA,
        const float* __restrict__ bfold,
        float* __restrict__ qa, float* __restrict__ ka,
        float* __restrict__ e_log) {
    __shared__ short pB[16 * 768];    // 24KB
    __shared__ short qB[16 * 768];    // 24KB
    __shared__ float gbl[2 * 768];    // 6KB
    __shared__ float2 pstat[16];      // (sum, sumsq) per staged P row
    __shared__ float2 qstat[16];

    const int tid = threadIdx.x;

    if (blockIdx.z >= BB) {
        // ---------------- qk role: one wave per output ----------------
        int qb = (blockIdx.z - BB) * 64 + blockIdx.y * 8 + blockIdx.x;   // 0..1535
        int wid = qb * 8 + (tid >> 6);                                   // 0..12287
        int lane = tid & 63;
        int which = wid & 1;
        int r = wid >> 1;
        int h = r % HH;
        int t = (r / HH) % NSl;
        int b = r / (HH * NSl);
        const float* W = (which ? WKA : WQA) + h * DD;
        const float* row = nve + (b * NSl + t) * DD;
        float s = 0.f;
        #pragma unroll
        for (int rr = 0; rr < 12; ++rr) {
            int c = lane + 64 * rr;
            s += row[c] * W[c];
        }
        #pragma unroll
        for (int off = 32; off; off >>= 1) s += __shfl_xor(s, off);
        if (lane == 0)
            (which ? ka : qa)[(b * NSl + t) * HH + h] = s + bfold[12 + which * 12 + h];
        return;
    }

    // ---------------- pair role ----------------
    const int b   = blockIdx.z;
    const int pi0 = blockIdx.y * 16, qj0 = blockIdx.x * 16;

    // ---- stage bf16 P,Q rows (swizzled) + in-block row stats ----
    {
        int row = tid >> 5;
        int ccb = tid & 31;
        const unsigned short* psrc = Pu + (b * SS + min(pi0 + row, SS - 1)) * DD;
        const unsigned short* qsrc = Qu + (b * SS + min(qj0 + row, SS - 1)) * DD;
        float ps = 0.f, pss = 0.f, qs = 0.f, qss = 0.f;
        float f[8];
        #pragma unroll
        for (int it = 0; it < 3; ++it) {
            int cc = ccb + it * 32;
            int byte = (row * 1536 + cc * 16) ^ ((row & 7) << 4);
            short8 pv = *(const short8*)(psrc + cc * 8);
            unpack8(pv, f);
            #pragma unroll
            for (int q = 0; q < 8; ++q) { ps += f[q]; pss += f[q] * f[q]; }
            *(short8*)((char*)pB + byte) = pv;
            short8 qv = *(const short8*)(qsrc + cc * 8);
            unpack8(qv, f);
            #pragma unroll
            for (int q = 0; q < 8; ++q) { qs += f[q]; qss += f[q] * f[q]; }
            *(short8*)((char*)qB + byte) = qv;
        }
        #pragma unroll
        for (int off = 16; off; off >>= 1) {
            ps  += __shfl_xor(ps, off);
            pss += __shfl_xor(pss, off);
            qs  += __shfl_xor(qs, off);
            qss += __shfl_xor(qss, off);
        }
        if ((tid & 31) == 0) {
            pstat[tid >> 5] = make_float2(ps, pss);
            qstat[tid >> 5] = make_float2(qs, qss);
        }
    }
    if (tid < 384) {
        int c = tid * 4;
        float4 v = (tid < 192) ? *(const float4*)(ln_g + c)
                               : *(const float4*)(ln_b + (c - 768));
        *(float4*)(gbl + c) = v;
    }
    __syncthreads();

    const int lane = tid & 63;
    const int w    = tid >> 6;
    const int l15  = lane & 15;
    const int kg   = lane >> 4;

    // ---- in-block Gram ----
    f32x4 gacc = {};
    #pragma unroll 4
    for (int ks = 0; ks < 24; ++ks) {
        int cb = ks * 64 + kg * 16;
        short8 ap = *(const short8*)((char*)pB + ((l15 * 1536 + cb) ^ ((l15 & 7) << 4)));
        short8 aq = *(const short8*)((char*)qB + ((l15 * 1536 + cb) ^ ((l15 & 7) << 4)));
        gacc = __builtin_amdgcn_mfma_f32_16x16x32_bf16(ap, aq, gacc, 0, 0, 0);
    }

    // ---- per-pair LN scalars ----
    float al[2], be[2];
    #pragma unroll
    for (int s = 0; s < 2; ++s) {
        int pl = 2 * w + s;
        int src = ((pl >> 2) << 4) | l15;
        int rsel = pl & 3;
        float gg = (rsel == 0) ? gacc[0] : (rsel == 1) ? gacc[1]
                 : (rsel == 2) ? gacc[2] : gacc[3];
        gg = __shfl(gg, src);
        float2 pst = pstat[pl];
        float2 qst = qstat[l15];
        float mean = (pst.x + qst.x) * (1.f / DD);
        float sumsq = pst.y + 2.f * gg + qst.y;
        float var = sumsq * (1.f / DD) - mean * mean;
        float a = rsqrtf(var + 1e-5f);
        al[s] = a;
        be[s] = -mean * a;
    }

    // ---- main loop ----
    const unsigned short* wrow = W2Bu + l15 * 768;
    const int r0 = 2 * w, r1 = 2 * w + 1;
    const int p0base = r0 * 1536, p1base = r1 * 1536;
    const int p0x = (r0 & 7) << 4, p1x = (r1 & 7) << 4;
    f32x4 acc0 = {}, acc1 = {};

    #pragma unroll 2
    for (int ks = 0; ks < 24; ++ks) {
        const int c0 = ks * 32 + kg * 8;
        short8 bfg = *(const short8*)(wrow + c0);
        f32x4 g0 = *(const f32x4*)(gbl + c0);
        f32x4 g1 = *(const f32x4*)(gbl + c0 + 4);
        f32x4 bb0 = *(const f32x4*)(gbl + 768 + c0);
        f32x4 bb1 = *(const f32x4*)(gbl + 768 + c0 + 4);
        float gv[8] = {g0.x, g0.y, g0.z, g0.w, g1.x, g1.y, g1.z, g1.w};
        float bv8[8] = {bb0.x, bb0.y, bb0.z, bb0.w, bb1.x, bb1.y, bb1.z, bb1.w};

        short8 q8 = *(const short8*)((char*)qB + ((l15 * 1536 + c0 * 2) ^ ((l15 & 7) << 4)));
        float qf[8];
        unpack8(q8, qf);

        short8 p8 = *(const short8*)((char*)pB + ((p0base + c0 * 2) ^ p0x));
        float pf[8];
        unpack8(p8, pf);
        float y[8];
        #pragma unroll
        for (int j = 0; j < 8; ++j) {
            float t = pf[j] + qf[j];
            float u = __builtin_fmaf(al[0], t, be[0]);
            y[j] = fmaxf(__builtin_fmaf(gv[j], u, bv8[j]), 0.f);
        }
        {
            int4 ti = { (int)cvtpk(y[0], y[1]), (int)cvtpk(y[2], y[3]),
                        (int)cvtpk(y[4], y[5]), (int)cvtpk(y[6], y[7]) };
            short8 ya = __builtin_bit_cast(short8, ti);
            acc0 = __builtin_amdgcn_mfma_f32_16x16x32_bf16(ya, bfg, acc0, 0, 0, 0);
        }

        p8 = *(const short8*)((char*)pB + ((p1base + c0 * 2) ^ p1x));
        unpack8(p8, pf);
        #pragma unroll
        for (int j = 0; j < 8; ++j) {
            float t = pf[j] + qf[j];
            float u = __builtin_fmaf(al[1], t, be[1]);
            y[j] = fmaxf(__builtin_fmaf(gv[j], u, bv8[j]), 0.f);
        }
        {
            int4 ti = { (int)cvtpk(y[0], y[1]), (int)cvtpk(y[2], y[3]),
                        (int)cvtpk(y[4], y[5]), (int)cvtpk(y[6], y[7]) };
            short8 ya = __builtin_bit_cast(short8, ti);
            acc1 = __builtin_amdgcn_mfma_f32_16x16x32_bf16(ya, bfg, acc1, 0, 0, 0);
        }
    }

    if (l15 < HH) {
        const float badd = bfold[l15];
        #pragma unroll
        for (int s = 0; s < 2; ++s) {
            int pig = pi0 + 2 * w + s;
            if (pig >= SS) continue;
            f32x4 A = s ? acc1 : acc0;
            #pragma unroll
            for (int r = 0; r < 4; ++r) {
                int qjg = qj0 + (kg << 2) + r;
                if (qjg < SS) {
                    int i = (pig == qjg) ? 0 : (pig + 1);
                    e_log[(((b * HH + l15) * NSl) + i) * NSl + (qjg + 1)] = A[r] + badd;
                }
            }
        }
    }
}

// ---------------------------------------------------------------------------
// Softmax + context: PV via MFMA; V read as bf16.
// ---------------------------------------------------------------------------
__global__ __launch_bounds__(512) void softmax_ctx_kernel(
        const float* __restrict__ e_log,
        const float* __restrict__ qa, const float* __restrict__ ka,
        const float* __restrict__ mask_M, const float* __restrict__ ab,
        const unsigned short* __restrict__ Vu,
        float* __restrict__ out) {
    __shared__ short Vt[64 * 128];    // [d][j] bf16 swizzled, 16KB
    __shared__ short plb[32 * 128];   // [i_loc][j] bf16 swizzled, 8KB
    __shared__ float kal[NSl];

    const int b = blockIdx.z;
    const int h = blockIdx.y;
    const int iq = blockIdx.x;
    const int tid = threadIdx.x;
    const int lane = tid & 63;
    const int w = tid >> 6;

    // ---- stage Vt (transposed bf16, swizzled) from bf16 V ----
    {
        int j = tid >> 2;
        int dq = (tid & 3) * 16;
        const unsigned short* src = Vu + (b * NSl + j) * DD + h * HDl + dq;
        short8 s0 = *(const short8*)(src);
        short8 s1 = *(const short8*)(src + 8);
        #pragma unroll
        for (int t = 0; t < 8; ++t) {
            int d = dq + t;
            *(short*)((char*)Vt + ((d * 256 + j * 2) ^ ((d & 7) << 4))) = s0[t];
        }
        #pragma unroll
        for (int t = 0; t < 8; ++t) {
            int d = dq + 8 + t;
            *(short*)((char*)Vt + ((d * 256 + j * 2) ^ ((d & 7) << 4))) = s1[t];
        }
    }
    if (tid < NSl) kal[tid] = ka[(b * NSl + tid) * HH + h];
    __syncthreads();

    const float abv = ab[0];

    // ---- softmax phase (no block barriers) ----
    for (int rr = 0; rr < 4; ++rr) {
        const int il = w * 4 + rr;           // local row 0..31
        const int i = iq * 32 + il;
        const float qv = qa[(b * NSl + i) * HH + h];
        const float* e_row = e_log + (((b * HH + h) * NSl) + i) * NSl;

        float lg[2];
        bool valid[2];
        #pragma unroll
        for (int s = 0; s < 2; ++s) {
            int j = 1 + lane + 64 * s;
            bool v = (j < NSl) && !(i >= 1 && j == i);
            float l = -1e30f;
            if (v) {
                l = e_row[j] + qv + kal[j] + abv;
                if (i >= 1) {
                    float p = mask_M[((b * HH + h) * SS + (i - 1)) * SS + (j - 1)];
                    p = fminf(fmaxf(p, 1e-6f), 1.0f - 1e-6f);
                    l += __logf(p / (1.0f - p));
                }
            }
            lg[s] = l;
            valid[s] = v;
        }
        float m = fmaxf(lg[0], lg[1]);
        #pragma unroll
        for (int off = 32; off; off >>= 1) m = fmaxf(m, __shfl_xor(m, off));
        float e0 = valid[0] ? __expf(lg[0] - m) : 0.f;
        float e1 = valid[1] ? __expf(lg[1] - m) : 0.f;
        float s = e0 + e1;
        #pragma unroll
        for (int off = 32; off; off >>= 1) s += __shfl_xor(s, off);
        const float inv = 1.0f / s;

        const float p0 = e0 * inv, p1 = e1 * inv;

        float* attn_row = out + BB * NSl * HH * HDl + (((b * HH + h) * NSl) + i) * NSl;
        attn_row[1 + lane] = p0;
        if (65 + lane < NSl) attn_row[65 + lane] = p1;
        if (lane == 0) attn_row[0] = 0.f;

        // probs -> plb bf16 (swizzled). Per-wave-private rows; no barrier.
        {
            int byte0 = (il * 256 + (1 + lane) * 2) ^ ((il & 7) << 4);
            *(short*)((char*)plb + byte0) = (short)f2bf(p0);
            if (65 + lane < NSl) {
                int byte1 = (il * 256 + (65 + lane) * 2) ^ ((il & 7) << 4);
                *(short*)((char*)plb + byte1) = (short)f2bf(p1);
            }
            if (lane == 0) {
                int byteZ = (il * 256) ^ ((il & 7) << 4);
                *(short*)((char*)plb + byteZ) = 0;
            }
        }
    }
    __syncthreads();

    // ---- context via MFMA: wave w -> itile = w>>2 (16 i), dtile = w&3 (16 d)
    const int l15 = lane & 15;
    const int kg  = lane >> 4;
    const int itile = w >> 2, dtile = w & 3;
    const int arow  = itile * 16 + l15;
    const int bcold = dtile * 16 + l15;
    f32x4 acc = {};
    #pragma unroll
    for (int ks = 0; ks < 4; ++ks) {
        int kb = (ks * 32 + kg * 8) * 2;
        short8 af = *(const short8*)((char*)plb + ((arow * 256 + kb) ^ ((arow & 7) << 4)));
        short8 bf = *(const short8*)((char*)Vt  + ((bcold * 256 + kb) ^ ((bcold & 7) << 4)));
        acc = __builtin_amdgcn_mfma_f32_16x16x32_bf16(af, bf, acc, 0, 0, 0);
    }
    #pragma unroll
    for (int r = 0; r < 4; ++r) {
        int i = iq * 32 + itile * 16 + kg * 4 + r;
        out[((b * NSl + i) * HH + h) * HDl + dtile * 16 + l15] = acc[r];
    }
}

// ---------------------------------------------------------------------------
extern "C" void kernel_launch(void* const* d_in, const int* in_sizes, int n_in,
                              void* d_out, int out_size, void* d_ws, size_t ws_size,
                              hipStream_t stream) {
    const float* desc   = (const float*)d_in[0];
    const float* nve    = (const float*)d_in[1];
    const float* mask_M = (const float*)d_in[2];
    const float* Wq     = (const float*)d_in[3];
    const float* bq     = (const float*)d_in[4];
    const float* Wk     = (const float*)d_in[5];
    const float* bk     = (const float*)d_in[6];
    const float* Wv     = (const float*)d_in[7];
    const float* bv     = (const float*)d_in[8];
    const float* eW1    = (const float*)d_in[9];
    const float* eb1    = (const float*)d_in[10];
    const float* ln_g   = (const float*)d_in[11];
    const float* ln_b   = (const float*)d_in[12];
    const float* eW2    = (const float*)d_in[13];
    const float* eb2    = (const float*)d_in[14];
    const float* aW     = (const float*)d_in[15];
    const float* ab     = (const float*)d_in[16];

    float* ws  = (float*)d_ws;
    float* out = (float*)d_out;
    unsigned short* Pu   = (unsigned short*)(ws + OFF_P);
    unsigned short* Qu   = (unsigned short*)(ws + OFF_Q);
    unsigned short* Vu   = (unsigned short*)(ws + OFF_V);
    unsigned short* W2Bu = (unsigned short*)(ws + OFF_W2B);

    mega1<<<NB_PQ + NB_V + NB_FOLD, 512, 0, stream>>>(
        desc, nve, eW1, Wv, bv, eb1,
        Wq, Wk, eW2, bq, bk, eb2, aW,
        Pu, Qu, Vu,
        W2Bu, ws + OFF_WQA, ws + OFF_WKA, ws + OFF_BF);

    pairqk_kernel<<<dim3(8, 8, BB + 24), 512, 0, stream>>>(
        Pu, Qu, nve, ln_g, ln_b, W2Bu,
        ws + OFF_WQA, ws + OFF_WKA, ws + OFF_BF,
        ws + OFF_QA, ws + OFF_KA, ws + OFF_EL);

    softmax_ctx_kernel<<<dim3(4, HH, BB), 512, 0, stream>>>(
        ws + OFF_EL, ws + OFF_QA, ws + OFF_KA, mask_M, ab, Vu, out);
}